// Round 11
// baseline (107.177 us; speedup 1.0000x reference)
//
#include <hip/hip_runtime.h>
#include <hip/hip_bf16.h>

#define N_NODES     100000
#define NODE_DIM    128
#define N_REL       32
#define N_EDGES_C   500000
#define H_DIM       192             // 3*MLP_DIM
#define P_COLS      384             // 2*H_DIM
#define TILE_ROWS   32
#define NTILES      3125            // ceil(100000/32)
#define NBLK        512             // 2 blocks per CU

typedef __bf16 bf16x8 __attribute__((ext_vector_type(8)));
typedef float  f32x4  __attribute__((ext_vector_type(4)));
typedef float  f32x2  __attribute__((ext_vector_type(2)));
typedef unsigned int u32;

__device__ __forceinline__ ushort f2b(float x) {
    __hip_bfloat16 h = __float2bfloat16(x);     // RNE
    return *reinterpret_cast<ushort*>(&h);
}

// async global->LDS, 16B per lane (dest = wave-uniform base + lane*16)
__device__ __forceinline__ void gload_lds16(const void* g, void* l) {
    __builtin_amdgcn_global_load_lds(
        (const __attribute__((address_space(1))) u32*)g,
        (__attribute__((address_space(3))) u32*)l, 16, 0, 0);
}

// ---------------------------------------------------------------------------
// Kernel B: Bmat[c][k] = bf16(Beff), c in [0,384), k in [0,128)
// ---------------------------------------------------------------------------
__global__ __launch_bounds__(256) void build_b_kernel(
        const float* __restrict__ W1, ushort* __restrict__ Bmat) {
    int idx = blockIdx.x * 256 + threadIdx.x;      // 49152 total
    if (idx >= P_COLS * NODE_DIM) return;
    int c = idx >> 7, k = idx & 127;
    float v = (c < H_DIM) ? W1[(size_t)c * P_COLS + k]
                          : W1[(size_t)(c - H_DIM) * P_COLS + NODE_DIM + k];
    Bmat[idx] = f2b(v);
}

// ---------------------------------------------------------------------------
// Kernel C: Rb[r][j] = b1[j] + sum_k relation_emb[r][k] * W1[j][256+k]  (f32)
// ---------------------------------------------------------------------------
__global__ void rel_precompute_kernel(const float* __restrict__ rel,
                                      const float* __restrict__ W1,
                                      const float* __restrict__ b1,
                                      float* __restrict__ Rb) {
    int r = blockIdx.x;
    int j = threadIdx.x;           // 0..191
    const float* re = rel + r * NODE_DIM;
    const float* w  = W1 + (size_t)j * P_COLS + 2 * NODE_DIM;
    float acc = b1[j];
    #pragma unroll 8
    for (int k = 0; k < NODE_DIM; ++k)
        acc = fmaf(re[k], w[k], acc);
    Rb[r * H_DIM + j] = acc;
}

// ---------------------------------------------------------------------------
// Kernel D: MFMA GEMM, async LDS staging, 3-buffer depth-2 pipeline with
// COUNTED vmcnt (never 0 mid-loop).  512 blocks (2/CU), 256 thr = 4 waves.
// (unchanged from r9/r10 — verified)
// ---------------------------------------------------------------------------
__global__ __launch_bounds__(256) void node_mfma_kernel(
        const float* __restrict__ embF,
        const ushort* __restrict__ Bmat,
        ushort* __restrict__ Pb) {
    __shared__ float ldsA[3][TILE_ROWS * NODE_DIM];   // 3 x 16 KB

    const int tid  = threadIdx.x;
    const int wid  = tid >> 6;
    const int lane = tid & 63;
    const int r16  = lane & 15;
    const int kgrp = lane >> 4;
    const int colw = wid * 96;

    bf16x8 Bf[6][4];
    {
        const ushort* Bbase = Bmat + (size_t)(colw + r16) * NODE_DIM + kgrp * 8;
        #pragma unroll
        for (int ct = 0; ct < 6; ++ct)
            #pragma unroll
            for (int ks = 0; ks < 4; ++ks)
                Bf[ct][ks] = *(const bf16x8*)(Bbase + (size_t)ct * 16 * NODE_DIM + ks * 32);
    }

    const size_t A_CLAMP = (size_t)N_NODES * NODE_DIM * sizeof(float) - 16;

    auto stage = [&](int p, int tile) {
        const size_t tbase = (size_t)tile * (TILE_ROWS * NODE_DIM * 4);
        #pragma unroll
        for (int i = 0; i < 4; ++i) {
            const int L    = i * 4096 + tid * 16;     // 0..16368
            const int u16  = L >> 4;                  // 16B unit 0..1023
            const int rowl = u16 >> 5;                // 0..31
            const int g16  = u16 & 31;                // 16B granule in row
            size_t src = tbase +
                (size_t)((rowl << 9) | ((g16 ^ rowl) << 4));
            if (src > A_CLAMP) src = A_CLAMP;         // pad rows: garbage, guarded
            gload_lds16((const char*)embF + src, (char*)&ldsA[p][0] + L);
        }
    };

    int tile = blockIdx.x;
    stage(0, tile);
    if (tile + NBLK < NTILES) stage(1, tile + NBLK);
    int p = 0;

    for (; tile < NTILES; tile += NBLK) {
        const bool more1 = (tile + NBLK)     < NTILES;
        const bool more2 = (tile + 2 * NBLK) < NTILES;

        if (more1) asm volatile("s_waitcnt vmcnt(4)" ::: "memory");
        else       asm volatile("s_waitcnt vmcnt(0)" ::: "memory");
        __builtin_amdgcn_s_barrier();

        if (more2) stage((p + 2) % 3, tile + 2 * NBLK);   // depth-2 prefetch

        bf16x8 a[2][4];
        #pragma unroll
        for (int rt = 0; rt < 2; ++rt) {
            const int rowl = rt * 16 + r16;           // 0..31
            #pragma unroll
            for (int ks = 0; ks < 4; ++ks) {
                const int gbase = 2 * (kgrp + ks * 4);
                const float* pa = &ldsA[p][rowl * NODE_DIM + ((gbase    ) ^ rowl) * 4];
                const float* pb = &ldsA[p][rowl * NODE_DIM + ((gbase + 1) ^ rowl) * 4];
                float4 v0 = *(const float4*)pa;
                float4 v1 = *(const float4*)pb;
                bf16x8 r;
                r[0] = (__bf16)v0.x; r[1] = (__bf16)v0.y;
                r[2] = (__bf16)v0.z; r[3] = (__bf16)v0.w;
                r[4] = (__bf16)v1.x; r[5] = (__bf16)v1.y;
                r[6] = (__bf16)v1.z; r[7] = (__bf16)v1.w;
                a[rt][ks] = r;
            }
        }

        f32x4 acc[2][6] = {};
        #pragma unroll
        for (int ks = 0; ks < 4; ++ks)
            #pragma unroll
            for (int ct = 0; ct < 6; ++ct) {
                acc[0][ct] = __builtin_amdgcn_mfma_f32_16x16x32_bf16(Bf[ct][ks], a[0][ks], acc[0][ct], 0, 0, 0);
                acc[1][ct] = __builtin_amdgcn_mfma_f32_16x16x32_bf16(Bf[ct][ks], a[1][ks], acc[1][ct], 0, 0, 0);
            }

        const int rowbase = tile * TILE_ROWS;
        #pragma unroll
        for (int rt = 0; rt < 2; ++rt) {
            const int prow = rowbase + rt * 16 + r16;
            if (prow < N_NODES) {
                ushort* rowp = Pb + (size_t)prow * P_COLS + colw + kgrp * 4;
                #pragma unroll
                for (int ct = 0; ct < 6; ++ct) {
                    unsigned lo = (unsigned)f2b(acc[rt][ct][0]) |
                                  ((unsigned)f2b(acc[rt][ct][1]) << 16);
                    unsigned hi = (unsigned)f2b(acc[rt][ct][2]) |
                                  ((unsigned)f2b(acc[rt][ct][3]) << 16);
                    uint2 v; v.x = lo; v.y = hi;
                    *(uint2*)(rowp + ct * 16) = v;
                }
            }
        }

        p = (p + 1) % 3;
    }
}

// ---------------------------------------------------------------------------
// Kernel E: TWO EDGES PER 8-LANE GROUP, with a sched_barrier(0) fence between
// the 12-load gather block and the math. The fence forbids the backend from
// sinking loads into the consumption stream (r10 evidence: VGPR=36 proved it
// serialized them), forcing all 12 uint4 results live -> ~2x outstanding
// random lines per wave. Semantically a no-op.
// ---------------------------------------------------------------------------
__device__ __forceinline__ void pairproc(unsigned h, unsigned t,
                                         f32x2 r, f32x2 w, f32x2& acc) {
    union { unsigned u[2]; f32x2 f; } A, B;
    A.u[0] = h << 16;          A.u[1] = h & 0xffff0000u;
    B.u[0] = t << 16;          B.u[1] = t & 0xffff0000u;
    f32x2 s = A.f + B.f + r;
#if __has_builtin(__builtin_elementwise_max)
    s = __builtin_elementwise_max(s, (f32x2)(0.f));
#else
    s[0] = fmaxf(s[0], 0.f); s[1] = fmaxf(s[1], 0.f);
#endif
    acc += s * w;              // fp-contract -> v_pk_fma_f32
}

__device__ __forceinline__ float gate_out(float weight, float uu) {
    float eps = fmaf(-0.9998f, uu, 0.9999f);                 // (2B-1)*u + (1-B)
    float gi  = (logf(eps) - log1pf(-eps) + weight) * 2.0f;  // / TEMPERATURE
    return 1.f / (1.f + expf(-gi));
}

__global__ __launch_bounds__(256) void edge_kernel(
        const int* __restrict__ edge_index,
        const int* __restrict__ edge_type,
        const ushort* __restrict__ Pb,
        const float* __restrict__ Rb,
        const float* __restrict__ u,
        const float* __restrict__ W2,
        const float* __restrict__ b2,
        float* __restrict__ out) {
    const int tid  = threadIdx.x;
    const int wave = tid >> 6;
    const int lane = tid & 63;
    const int g    = lane >> 3;       // edge-group slot within wave, 0..7
    const int sub  = lane & 7;        // element-chunk slot, 0..7

    const int e0 = blockIdx.x * 64 + wave * 16 + g;
    const int e1 = e0 + 8;
    const int eA = min(e0, N_EDGES_C - 1);
    const int eB = min(e1, N_EDGES_C - 1);

    const int headA = edge_index[eA];
    const int tailA = edge_index[N_EDGES_C + eA];
    const int relA  = edge_type[eA];
    const int headB = edge_index[eB];
    const int tailB = edge_index[N_EDGES_C + eB];
    const int relB  = edge_type[eB];

    const int j0 = sub * 8;
    const ushort* PhA = Pb + (size_t)headA * P_COLS + j0;           // cols 0:192
    const ushort* PtA = Pb + (size_t)tailA * P_COLS + H_DIM + j0;   // cols 192:384
    const ushort* PhB = Pb + (size_t)headB * P_COLS + j0;
    const ushort* PtB = Pb + (size_t)tailB * P_COLS + H_DIM + j0;

    // 12 independent random-line loads, all issued before any math
    uint4 hA0 = *(const uint4*)(PhA);
    uint4 hA1 = *(const uint4*)(PhA + 64);
    uint4 hA2 = *(const uint4*)(PhA + 128);
    uint4 tA0 = *(const uint4*)(PtA);
    uint4 tA1 = *(const uint4*)(PtA + 64);
    uint4 tA2 = *(const uint4*)(PtA + 128);
    uint4 hB0 = *(const uint4*)(PhB);
    uint4 hB1 = *(const uint4*)(PhB + 64);
    uint4 hB2 = *(const uint4*)(PhB + 128);
    uint4 tB0 = *(const uint4*)(PtB);
    uint4 tB1 = *(const uint4*)(PtB + 64);
    uint4 tB2 = *(const uint4*)(PtB + 128);

    // fence: no instruction may cross -> all 12 loads stay issued & live here
    __builtin_amdgcn_sched_barrier(0);

    const float* RrA = Rb + relA * H_DIM + j0;   // L1-resident (24KB table)
    const float* RrB = Rb + relB * H_DIM + j0;
    const float* Wp  = W2 + j0;                  // L1-resident (768B)

    f32x2 accA = {0.f, 0.f}, accB = {0.f, 0.f};
    #pragma unroll
    for (int c = 0; c < 3; ++c) {
        uint4 hvA = (c == 0) ? hA0 : (c == 1) ? hA1 : hA2;
        uint4 tvA = (c == 0) ? tA0 : (c == 1) ? tA1 : tA2;
        uint4 hvB = (c == 0) ? hB0 : (c == 1) ? hB1 : hB2;
        uint4 tvB = (c == 0) ? tB0 : (c == 1) ? tB1 : tB2;
        f32x4 rAa = *(const f32x4*)(RrA + c * 64);
        f32x4 rAb = *(const f32x4*)(RrA + c * 64 + 4);
        f32x4 rBa = *(const f32x4*)(RrB + c * 64);
        f32x4 rBb = *(const f32x4*)(RrB + c * 64 + 4);
        f32x4 w4a = *(const f32x4*)(Wp + c * 64);
        f32x4 w4b = *(const f32x4*)(Wp + c * 64 + 4);

        pairproc(hvA.x, tvA.x, rAa.xy, w4a.xy, accA);
        pairproc(hvB.x, tvB.x, rBa.xy, w4a.xy, accB);
        pairproc(hvA.y, tvA.y, rAa.zw, w4a.zw, accA);
        pairproc(hvB.y, tvB.y, rBa.zw, w4a.zw, accB);
        pairproc(hvA.z, tvA.z, rAb.xy, w4b.xy, accA);
        pairproc(hvB.z, tvB.z, rBb.xy, w4b.xy, accB);
        pairproc(hvA.w, tvA.w, rAb.zw, w4b.zw, accA);
        pairproc(hvB.w, tvB.w, rBb.zw, w4b.zw, accB);
    }

    float ra = accA[0] + accA[1];
    float rb = accB[0] + accB[1];
    ra += __shfl_xor(ra, 1);  rb += __shfl_xor(rb, 1);
    ra += __shfl_xor(ra, 2);  rb += __shfl_xor(rb, 2);
    ra += __shfl_xor(ra, 4);  rb += __shfl_xor(rb, 4);

    if (sub == 0) {
        const float bb = b2[0];
        if (e0 < N_EDGES_C) out[e0] = gate_out(ra + bb, u[e0]);
        if (e1 < N_EDGES_C) out[e1] = gate_out(rb + bb, u[e1]);
    }
}

// ---------------------------------------------------------------------------
extern "C" void kernel_launch(void* const* d_in, const int* in_sizes, int n_in,
                              void* d_out, int out_size, void* d_ws, size_t ws_size,
                              hipStream_t stream) {
    const int*   edge_index   = (const int*)d_in[0];
    const int*   edge_type    = (const int*)d_in[1];
    const float* all_embed    = (const float*)d_in[2];
    const float* relation_emb = (const float*)d_in[3];
    const float* u            = (const float*)d_in[4];
    const float* W1           = (const float*)d_in[5];
    const float* b1           = (const float*)d_in[6];
    const float* W2           = (const float*)d_in[7];
    const float* b2           = (const float*)d_in[8];
    float*       out          = (float*)d_out;

    char* ws = (char*)d_ws;
    ushort* Bmat = (ushort*)ws;                                   // 384 x 128 bf16
    ws += (size_t)P_COLS * NODE_DIM * sizeof(ushort);
    float*  Rb   = (float*)ws;                                    // 32 x 192 f32
    ws += (size_t)N_REL * H_DIM * sizeof(float);
    ushort* Pb   = (ushort*)ws;                                   // 100000 x 384 bf16

    build_b_kernel<<<(P_COLS * NODE_DIM + 255) / 256, 256, 0, stream>>>(W1, Bmat);
    rel_precompute_kernel<<<N_REL, H_DIM, 0, stream>>>(relation_emb, W1, b1, Rb);

    node_mfma_kernel<<<NBLK, 256, 0, stream>>>(all_embed, Bmat, Pb);

    edge_kernel<<<(N_EDGES_C + 63) / 64, 256, 0, stream>>>(
        edge_index, edge_type, Pb, Rb, u, W2, b2, out);
}

// Round 12
// 97.672 us; speedup vs baseline: 1.0973x; 1.0973x over previous
//
#include <hip/hip_runtime.h>
#include <hip/hip_bf16.h>

#define N_NODES     100000
#define NODE_DIM    128
#define N_REL       32
#define N_EDGES_C   500000
#define H_DIM       192             // 3*MLP_DIM
#define P_COLS      384             // 2*H_DIM
#define TILE_ROWS   32
#define NTILES      3125            // ceil(100000/32)
#define NBLK        512             // 2 blocks per CU

typedef __bf16 bf16x8 __attribute__((ext_vector_type(8)));
typedef float  f32x4  __attribute__((ext_vector_type(4)));
typedef float  f32x2  __attribute__((ext_vector_type(2)));
typedef unsigned int u32;

__device__ __forceinline__ ushort f2b(float x) {
    __hip_bfloat16 h = __float2bfloat16(x);     // RNE
    return *reinterpret_cast<ushort*>(&h);
}

// async global->LDS, 16B per lane (dest = wave-uniform base + lane*16)
__device__ __forceinline__ void gload_lds16(const void* g, void* l) {
    __builtin_amdgcn_global_load_lds(
        (const __attribute__((address_space(1))) u32*)g,
        (__attribute__((address_space(3))) u32*)l, 16, 0, 0);
}

// ---------------------------------------------------------------------------
// Fused prep kernel (one launch instead of two):
//   blocks [0,192):  Bmat[c][k] = bf16(Beff)   (49152 elements)
//   blocks [192,224): Rb[r][j] = b1[j] + dot(relation_emb[r], W1[j][256:384])
// ---------------------------------------------------------------------------
__global__ __launch_bounds__(256) void prep_kernel(
        const float* __restrict__ W1,
        const float* __restrict__ rel,
        const float* __restrict__ b1,
        ushort* __restrict__ Bmat,
        float* __restrict__ Rb) {
    if (blockIdx.x < 192) {
        int idx = blockIdx.x * 256 + threadIdx.x;
        int c = idx >> 7, k = idx & 127;
        float v = (c < H_DIM) ? W1[(size_t)c * P_COLS + k]
                              : W1[(size_t)(c - H_DIM) * P_COLS + NODE_DIM + k];
        Bmat[idx] = f2b(v);
    } else {
        int r = blockIdx.x - 192;
        int j = threadIdx.x;
        if (j < H_DIM) {
            const float* re = rel + r * NODE_DIM;
            const float* w  = W1 + (size_t)j * P_COLS + 2 * NODE_DIM;
            float acc = b1[j];
            #pragma unroll 8
            for (int k = 0; k < NODE_DIM; ++k)
                acc = fmaf(re[k], w[k], acc);
            Rb[r * H_DIM + j] = acc;
        }
    }
}

// ---------------------------------------------------------------------------
// Kernel D: MFMA GEMM, async LDS staging, 4-buffer DEPTH-3 pipeline with
// counted vmcnt (8/4/0).  512 blocks (2/CU), 256 thr = 4 waves.
// Per tile: 32 rows x 384 cols; wave = 32 rows x 96 cols (wc = wid).
// B persistent in 96 VGPRs; LDS 16B-granule XOR swizzle on both sides.
// Swapped-operand MFMA: lane holds 4 consecutive P-cols of one node row.
// ---------------------------------------------------------------------------
__global__ __launch_bounds__(256) void node_mfma_kernel(
        const float* __restrict__ embF,
        const ushort* __restrict__ Bmat,
        ushort* __restrict__ Pb) {
    __shared__ float ldsA[4][TILE_ROWS * NODE_DIM];   // 4 x 16 KB

    const int tid  = threadIdx.x;
    const int wid  = tid >> 6;
    const int lane = tid & 63;
    const int r16  = lane & 15;
    const int kgrp = lane >> 4;
    const int colw = wid * 96;

    bf16x8 Bf[6][4];
    {
        const ushort* Bbase = Bmat + (size_t)(colw + r16) * NODE_DIM + kgrp * 8;
        #pragma unroll
        for (int ct = 0; ct < 6; ++ct)
            #pragma unroll
            for (int ks = 0; ks < 4; ++ks)
                Bf[ct][ks] = *(const bf16x8*)(Bbase + (size_t)ct * 16 * NODE_DIM + ks * 32);
    }

    const size_t A_CLAMP = (size_t)N_NODES * NODE_DIM * sizeof(float) - 16;

    auto stage = [&](int p, int tile) {
        const size_t tbase = (size_t)tile * (TILE_ROWS * NODE_DIM * 4);
        #pragma unroll
        for (int i = 0; i < 4; ++i) {
            const int L    = i * 4096 + tid * 16;     // 0..16368
            const int u16  = L >> 4;                  // 16B unit 0..1023
            const int rowl = u16 >> 5;                // 0..31
            const int g16  = u16 & 31;                // 16B granule in row
            size_t src = tbase +
                (size_t)((rowl << 9) | ((g16 ^ rowl) << 4));
            if (src > A_CLAMP) src = A_CLAMP;         // pad rows: garbage, guarded
            gload_lds16((const char*)embF + src, (char*)&ldsA[p][0] + L);
        }
    };

    int tile = blockIdx.x;
    stage(0, tile);
    if (tile + NBLK     < NTILES) stage(1, tile + NBLK);
    if (tile + 2 * NBLK < NTILES) stage(2, tile + 2 * NBLK);
    int p = 0;

    for (; tile < NTILES; tile += NBLK) {
        const bool more1 = (tile + NBLK)     < NTILES;
        const bool more2 = (tile + 2 * NBLK) < NTILES;
        const bool more3 = (tile + 3 * NBLK) < NTILES;

        // wait for buf[p] only: keep newer tiles' loads in flight
        if      (more2) asm volatile("s_waitcnt vmcnt(8)" ::: "memory");
        else if (more1) asm volatile("s_waitcnt vmcnt(4)" ::: "memory");
        else            asm volatile("s_waitcnt vmcnt(0)" ::: "memory");
        __builtin_amdgcn_s_barrier();

        if (more3) stage((p + 3) & 3, tile + 3 * NBLK);   // depth-3 prefetch

        bf16x8 a[2][4];
        #pragma unroll
        for (int rt = 0; rt < 2; ++rt) {
            const int rowl = rt * 16 + r16;           // 0..31
            #pragma unroll
            for (int ks = 0; ks < 4; ++ks) {
                const int gbase = 2 * (kgrp + ks * 4);
                const float* pa = &ldsA[p][rowl * NODE_DIM + ((gbase    ) ^ rowl) * 4];
                const float* pb = &ldsA[p][rowl * NODE_DIM + ((gbase + 1) ^ rowl) * 4];
                float4 v0 = *(const float4*)pa;
                float4 v1 = *(const float4*)pb;
                bf16x8 r;
                r[0] = (__bf16)v0.x; r[1] = (__bf16)v0.y;
                r[2] = (__bf16)v0.z; r[3] = (__bf16)v0.w;
                r[4] = (__bf16)v1.x; r[5] = (__bf16)v1.y;
                r[6] = (__bf16)v1.z; r[7] = (__bf16)v1.w;
                a[rt][ks] = r;
            }
        }

        f32x4 acc[2][6] = {};
        #pragma unroll
        for (int ks = 0; ks < 4; ++ks)
            #pragma unroll
            for (int ct = 0; ct < 6; ++ct) {
                acc[0][ct] = __builtin_amdgcn_mfma_f32_16x16x32_bf16(Bf[ct][ks], a[0][ks], acc[0][ct], 0, 0, 0);
                acc[1][ct] = __builtin_amdgcn_mfma_f32_16x16x32_bf16(Bf[ct][ks], a[1][ks], acc[1][ct], 0, 0, 0);
            }

        const int rowbase = tile * TILE_ROWS;
        #pragma unroll
        for (int rt = 0; rt < 2; ++rt) {
            const int prow = rowbase + rt * 16 + r16;
            if (prow < N_NODES) {
                ushort* rowp = Pb + (size_t)prow * P_COLS + colw + kgrp * 4;
                #pragma unroll
                for (int ct = 0; ct < 6; ++ct) {
                    unsigned lo = (unsigned)f2b(acc[rt][ct][0]) |
                                  ((unsigned)f2b(acc[rt][ct][1]) << 16);
                    unsigned hi = (unsigned)f2b(acc[rt][ct][2]) |
                                  ((unsigned)f2b(acc[rt][ct][3]) << 16);
                    uint2 v; v.x = lo; v.y = hi;
                    *(uint2*)(rowp + ct * 16) = v;
                }
            }
        }

        p = (p + 1) & 3;
    }
}

// ---------------------------------------------------------------------------
// Kernel E: 8 LANES PER EDGE (r9-exact, best measured). Packed f32x2 math.
// ---------------------------------------------------------------------------
__device__ __forceinline__ void pairproc(unsigned h, unsigned t,
                                         f32x2 r, f32x2 w, f32x2& acc) {
    union { unsigned u[2]; f32x2 f; } A, B;
    A.u[0] = h << 16;          A.u[1] = h & 0xffff0000u;
    B.u[0] = t << 16;          B.u[1] = t & 0xffff0000u;
    f32x2 s = A.f + B.f + r;
#if __has_builtin(__builtin_elementwise_max)
    s = __builtin_elementwise_max(s, (f32x2)(0.f));
#else
    s[0] = fmaxf(s[0], 0.f); s[1] = fmaxf(s[1], 0.f);
#endif
    acc += s * w;              // fp-contract -> v_pk_fma_f32
}

__global__ __launch_bounds__(256) void edge_kernel(
        const int* __restrict__ edge_index,
        const int* __restrict__ edge_type,
        const ushort* __restrict__ Pb,
        const float* __restrict__ Rb,
        const float* __restrict__ u,
        const float* __restrict__ W2,
        const float* __restrict__ b2,
        float* __restrict__ out) {
    const int tid  = threadIdx.x;
    const int wave = tid >> 6;
    const int lane = tid & 63;
    const int g    = lane >> 3;       // edge slot within wave, 0..7
    const int sub  = lane & 7;        // element-chunk slot, 0..7

    const int e = blockIdx.x * 32 + wave * 8 + g;   // 15625*32 == 500000 exact

    const int head = edge_index[e];
    const int tail = edge_index[N_EDGES_C + e];
    const int rel  = edge_type[e];

    const ushort* Ph = Pb + (size_t)head * P_COLS;          // cols 0:192
    const ushort* Pt = Pb + (size_t)tail * P_COLS + H_DIM;  // cols 192:384
    const int j0 = sub * 8;                                  // this lane's base elem

    // issue all 6 random-row loads up front (independent, one line per group)
    uint4 h0 = *(const uint4*)(Ph + j0);
    uint4 h1 = *(const uint4*)(Ph + j0 + 64);
    uint4 h2 = *(const uint4*)(Ph + j0 + 128);
    uint4 t0 = *(const uint4*)(Pt + j0);
    uint4 t1 = *(const uint4*)(Pt + j0 + 64);
    uint4 t2 = *(const uint4*)(Pt + j0 + 128);

    const float* Rr = Rb + rel * H_DIM + j0;   // L1-resident (24KB table)
    const float* Wp = W2 + j0;                 // L1-resident (768B)

    f32x2 acc2 = {0.f, 0.f};
    #pragma unroll
    for (int c = 0; c < 3; ++c) {
        uint4 hv = (c == 0) ? h0 : (c == 1) ? h1 : h2;
        uint4 tv = (c == 0) ? t0 : (c == 1) ? t1 : t2;
        f32x4 r4a = *(const f32x4*)(Rr + c * 64);
        f32x4 r4b = *(const f32x4*)(Rr + c * 64 + 4);
        f32x4 w4a = *(const f32x4*)(Wp + c * 64);
        f32x4 w4b = *(const f32x4*)(Wp + c * 64 + 4);

        pairproc(hv.x, tv.x, r4a.xy, w4a.xy, acc2);
        pairproc(hv.y, tv.y, r4a.zw, w4a.zw, acc2);
        pairproc(hv.z, tv.z, r4b.xy, w4b.xy, acc2);
        pairproc(hv.w, tv.w, r4b.zw, w4b.zw, acc2);
    }

    float acc = acc2[0] + acc2[1];
    acc += __shfl_xor(acc, 1);
    acc += __shfl_xor(acc, 2);
    acc += __shfl_xor(acc, 4);

    if (sub == 0) {
        float weight = acc + b2[0];
        float uu  = u[e];
        float eps = fmaf(-0.9998f, uu, 0.9999f);                 // (2B-1)*u + (1-B)
        float gi  = (logf(eps) - log1pf(-eps) + weight) * 2.0f;  // / TEMPERATURE
        out[e] = 1.f / (1.f + expf(-gi));
    }
}

// ---------------------------------------------------------------------------
extern "C" void kernel_launch(void* const* d_in, const int* in_sizes, int n_in,
                              void* d_out, int out_size, void* d_ws, size_t ws_size,
                              hipStream_t stream) {
    const int*   edge_index   = (const int*)d_in[0];
    const int*   edge_type    = (const int*)d_in[1];
    const float* all_embed    = (const float*)d_in[2];
    const float* relation_emb = (const float*)d_in[3];
    const float* u            = (const float*)d_in[4];
    const float* W1           = (const float*)d_in[5];
    const float* b1           = (const float*)d_in[6];
    const float* W2           = (const float*)d_in[7];
    const float* b2           = (const float*)d_in[8];
    float*       out          = (float*)d_out;

    char* ws = (char*)d_ws;
    ushort* Bmat = (ushort*)ws;                                   // 384 x 128 bf16
    ws += (size_t)P_COLS * NODE_DIM * sizeof(ushort);
    float*  Rb   = (float*)ws;                                    // 32 x 192 f32
    ws += (size_t)N_REL * H_DIM * sizeof(float);
    ushort* Pb   = (ushort*)ws;                                   // 100000 x 384 bf16

    prep_kernel<<<224, 256, 0, stream>>>(W1, relation_emb, b1, Bmat, Rb);

    node_mfma_kernel<<<NBLK, 256, 0, stream>>>(all_embed, Bmat, Pb);

    edge_kernel<<<N_EDGES_C / 32, 256, 0, stream>>>(
        edge_index, edge_type, Pb, Rb, u, W2, b2, out);
}